// Round 2
// baseline (228.691 us; speedup 1.0000x reference)
//
#include <hip/hip_runtime.h>
#include <stdint.h>

#define D_DIM 4096
#define N_ROWS 8192

typedef __attribute__((ext_vector_type(8))) short bfrag8;
typedef __attribute__((ext_vector_type(4))) float facc4;
typedef unsigned long long u64;

__device__ __forceinline__ uint32_t pack_bf16x2(float lo, float hi) {
    union { float f; uint32_t u; } a, b;
    a.f = lo; b.f = hi;
    return (b.u & 0xFFFF0000u) | (a.u >> 16);   // truncate-to-bf16
}

// ---------------------------------------------------------------------------
// Kernel 0: A fp32 -> bf16, XOR-swizzled per-K-chunk image (verified).
// ---------------------------------------------------------------------------
__global__ void __launch_bounds__(256)
prep_A(const float* __restrict__ A, uint32_t* __restrict__ A_sw) {
    const int S = blockIdx.x * 256 + threadIdx.x;  // 0..65535
    const int c = S >> 10;
    const int s = S & 1023;
    const int n = s >> 3;
    const int g = (s & 7) ^ (n & 7);
    const float* src = A + (size_t)n * D_DIM + c * 64 + g * 8;
    float4 f0 = *(const float4*)(src);
    float4 f1 = *(const float4*)(src + 4);
    uint4 o;
    o.x = pack_bf16x2(f0.x, f0.y);
    o.y = pack_bf16x2(f0.z, f0.w);
    o.z = pack_bf16x2(f1.x, f1.y);
    o.w = pack_bf16x2(f1.z, f1.w);
    *(uint4*)(A_sw + (size_t)S * 4) = o;
}

// ---------------------------------------------------------------------------
// Kernel 1: fused GEMM + sign-pack with IN-BLOCK split-K.
// 256 blocks x 1024 threads = 16 waves = 4 K-split groups x (2x2 wave tile).
// Group g covers K range [g*1024, (g+1)*1024) with its own Ls/As buffers;
// all groups iterate in lockstep (block-wide barriers). After the K-loop,
// groups 1..3 dump fp32 accs into LDS (reusing As space, XOR-swizzled
// float4 slots); group 0 reduces and runs the verified ballot+fold epilogue.
// No global partials, no reduce_pack dispatch.
// (Resubmission of round-1 source: round-1 bench was an infra failure;
//  bounds/barrier/LDS audit found no GPU-fault path.)
// ---------------------------------------------------------------------------
__global__ void __launch_bounds__(1024, 4)
gemm_pack_fused(const float* __restrict__ L, const uint32_t* __restrict__ A_sw,
                u64* __restrict__ folded) {
    __shared__ ushort Ls[4][32 * 72];   // 18.4 KB
    __shared__ uint4  As[4][1024];      // 64 KB; reused as reduction buffer
    __shared__ u64 halves[2][32];

    const int tid  = threadIdx.x;       // 0..1023
    const int g    = tid >> 8;          // K-split group 0..3 (wave-uniform)
    const int t    = tid & 255;         // thread within group
    const int wg   = t >> 6;            // wave within group 0..3
    const int lane = tid & 63;
    const int row0 = blockIdx.x * 32;
    const int c  = lane & 15;
    const int q  = lane >> 4;
    const int wm = wg >> 1;
    const int wn = wg & 1;

    const int lrow = t >> 3;
    const int lf4  = t & 7;
    const float* lsrc = L + (size_t)(row0 + lrow) * D_DIM + g * 1024 + lf4 * 4;
    ushort* ldst = &Ls[g][lrow * 72 + lf4 * 4];

    facc4 acc[4];
#pragma unroll
    for (int i = 0; i < 4; i++) acc[i] = (facc4){0.f, 0.f, 0.f, 0.f};

    for (int kc = 0; kc < 1024; kc += 64) {
        const uint32_t* gA = A_sw + (size_t)((g * 1024 + kc) >> 6) * 4096;
#pragma unroll
        for (int i = 0; i < 4; i++) {
            const int slot0 = wg * 256 + i * 64;
            __builtin_amdgcn_global_load_lds(
                (const __attribute__((address_space(1))) uint32_t*)(gA + (slot0 + lane) * 4),
                (__attribute__((address_space(3))) uint32_t*)(&As[g][slot0]),
                16, 0, 0);
        }
        float4 f0 = *(const float4*)(lsrc + kc);
        float4 f1 = *(const float4*)(lsrc + kc + 32);
        *(uint2*)ldst        = make_uint2(pack_bf16x2(f0.x, f0.y), pack_bf16x2(f0.z, f0.w));
        *(uint2*)(ldst + 32) = make_uint2(pack_bf16x2(f1.x, f1.y), pack_bf16x2(f1.z, f1.w));
        __syncthreads();

#pragma unroll
        for (int ks = 0; ks < 2; ks++) {
            bfrag8 a = *(const bfrag8*)&Ls[g][(16 * wm + c) * 72 + ks * 32 + q * 8];
#pragma unroll
            for (int ct = 0; ct < 4; ct++) {
                const int n  = 64 * wn + 16 * ct + c;
                const int gl = ks * 4 + q;
                bfrag8 b = *(const bfrag8*)&As[g][n * 8 + (gl ^ (n & 7))];
                acc[ct] = __builtin_amdgcn_mfma_f32_16x16x32_bf16(a, b, acc[ct], 0, 0, 0);
            }
        }
        __syncthreads();
    }

    // ---- cross-group reduction in LDS (reuse As: 16384 floats available,
    // need 3*4096). float4 slot index XOR-swizzled by (t>>1)&7 so the 16
    // lanes of a quarter-wave hit 8 distinct bank-quads (2-way = free).
    facc4* red = (facc4*)&As[0][0];
    const int sw = (t >> 1) & 7;
    if (g > 0) {
        facc4* dst = red + (g - 1) * 1024;
#pragma unroll
        for (int ct = 0; ct < 4; ct++)
            dst[(t * 4 + ct) ^ sw] = acc[ct];
    }
    __syncthreads();
    if (g == 0) {
#pragma unroll
        for (int s = 0; s < 3; s++) {
            const facc4* src = red + s * 1024;
#pragma unroll
            for (int ct = 0; ct < 4; ct++)
                acc[ct] += src[(t * 4 + ct) ^ sw];
        }
        // verified ballot + fold epilogue (gemm_pack, rounds 1-N):
        // lane (q,c) holds rows 16*wm+4*q+r, col 64*wn+16*ct+c.
        u64 masks[4][4];
#pragma unroll
        for (int ct = 0; ct < 4; ct++)
#pragma unroll
            for (int r = 0; r < 4; r++)
                masks[ct][r] = __ballot(acc[ct][r] > 0.0f);

        if (lane < 16) {
            const int qq = lane >> 2, r = lane & 3;
            u64 half = 0;
#pragma unroll
            for (int ct = 0; ct < 4; ct++) {
                u64 bits = (masks[ct][r] >> (16 * qq)) & 0xFFFFull;
                half |= bits << (16 * ct);
            }
            halves[wn][16 * wm + lane] = half;
        }
    }
    __syncthreads();
    if (tid < 32)
        folded[row0 + tid] = halves[0][tid] ^ halves[1][tid];
}

// ---------------------------------------------------------------------------
// Kernel 2: ordered duplicate count, LDS-staged keys, load-balanced rows
// (verified, unchanged).
// ---------------------------------------------------------------------------
__global__ void __launch_bounds__(512)
count_rows(const u64* __restrict__ folded, float* __restrict__ out) {
    __shared__ u64 K[N_ROWS];
    const int tid = threadIdx.x;
    for (int i = tid; i < N_ROWS; i += 512) K[i] = folded[i];
    __syncthreads();

    const int g    = blockIdx.x * 8 + (tid >> 6);   // 0..2047
    const int lane = tid & 63;
    int rows[4];
    u64 my[4];
    int cnt[4] = {0, 0, 0, 0};
#pragma unroll
    for (int r = 0; r < 4; r++) {
        rows[r] = g + 2048 * r;
        my[r] = K[rows[r]];
    }
    const int maxrow = rows[3];
    for (int j = lane; j <= maxrow; j += 64) {
        u64 k = K[j];
#pragma unroll
        for (int r = 0; r < 4; r++)
            cnt[r] += (int)((j <= rows[r]) & (k == my[r]));
    }
#pragma unroll
    for (int r = 0; r < 4; r++) {
        int v = cnt[r];
#pragma unroll
        for (int o = 32; o; o >>= 1) v += __shfl_xor(v, o, 64);
        if (lane == 0) out[rows[r]] = rsqrtf((float)v);
    }
}

extern "C" void kernel_launch(void* const* d_in, const int* in_sizes, int n_in,
                              void* d_out, int out_size, void* d_ws, size_t ws_size,
                              hipStream_t stream) {
    const float* latent = (const float*)d_in[0];   // [128,64,4096] fp32
    const float* A      = (const float*)d_in[1];   // [128,4096] fp32
    float* out          = (float*)d_out;           // [8192] fp32

    uint32_t* A_sw = (uint32_t*)d_ws;                               // 1 MB
    u64* folded = (u64*)((char*)d_ws + (1 << 20));                  // 64 KB

    prep_A<<<256, 256, 0, stream>>>(A, A_sw);
    gemm_pack_fused<<<256, 1024, 0, stream>>>(latent, A_sw, folded);
    count_rows<<<256, 512, 0, stream>>>(folded, out);
}